// Round 1
// baseline (79.975 us; speedup 1.0000x reference)
//
#include <hip/hip_runtime.h>
#include <math.h>

namespace {
constexpr int   T_STEPS = 400;
constexpr int   HALF    = 200;           // T/2 — scan covers t = 1..200
constexpr int   NPIX    = 250 * 400;     // H*W
constexpr int   CHUNK   = 32;            // timesteps per load chunk (fits uint32 mask)
constexpr int   BLOCK   = 256;
constexpr int   NBLK    = (NPIX + BLOCK - 1) / BLOCK;  // 391
constexpr float U0      = 0.15f;
constexpr float FSMALL  = 0.15f;
// D_CONST = 1.0, F_CONST = 10.0 hard-coded below
}

__global__ __launch_bounds__(BLOCK) void stp_compute(
    const float* __restrict__ spikes, float* __restrict__ img,
    float* __restrict__ pmin, float* __restrict__ pmax) {
  const int  p      = blockIdx.x * BLOCK + threadIdx.x;
  const bool active = (p < NPIX);
  bool  done = !active;
  int   prev = -1;        // last spike index seen (prev_strict for t > prev)
  float R = 1.0f, u = U0;

  for (int t0 = 0; t0 < T_STEPS; t0 += CHUNK) {
    // uniform per-block early exit once every lane has processed a spike >= HALF
    if (__syncthreads_and(done ? 1 : 0)) break;
    if (!done) {
      // statically-indexed unrolled loads -> spike bitmask (no scratch array)
      unsigned mask = 0u;
#pragma unroll
      for (int i = 0; i < CHUNK; ++i) {
        const float v = spikes[(size_t)(t0 + i) * NPIX + p];
        mask |= (v > 0.0f) ? (1u << i) : 0u;
      }
      while (mask) {
        const int i = __builtin_ctz(mask);
        mask &= mask - 1u;
        const int t = t0 + i;
        if (prev >= 0) {
          const int delta = t - prev;
          const int e     = (t < HALF) ? t : HALF;   // clip segment to scan range
          int n = e - prev;                          // steps tt in (prev, e]
          if (e == t && delta != 1) n -= 1;          // spike endpoint: only if isi==1
          if (n > 0) {
            const float d  = (float)delta;
            const float eD = expf(-d);               // exp(-isi / D), D = 1
            const float eF = expf(-(d / 10.0f));     // exp(-isi / F), F = 10
            for (int k = 0; k < n; ++k) {
              const float Rn = 1.0f - (1.0f - R * (1.0f - u)) * eD;
              const float un = U0 + (u + FSMALL * (1.0f - u) - U0) * eF;
              R = Rn; u = un;
            }
          }
        }
        prev = t;
        if (t >= HALF) { done = true; break; }       // everything in [1,HALF] covered
      }
    }
  }

  float val = 0.0f;
  if (active) {
    // rho_u = -1/(F*log((u-U0)/(F-U0+u*(1-f)))) ; rho_R = -1/(D*log((1-R)/(1-R*(1-u))))
    const float lu = logf((u - U0) / (10.0f - U0 + u * (1.0f - FSMALL)));
    const float lR = logf((1.0f - R) / (1.0f - R * (1.0f - u)));
    val = (-1.0f / (10.0f * lu)) + (-1.0f / lR);
    img[p] = val;
  }

  // block min/max -> partials
  float vmin = active ? val : INFINITY;
  float vmax = active ? val : -INFINITY;
#pragma unroll
  for (int off = 32; off > 0; off >>= 1) {
    vmin = fminf(vmin, __shfl_down(vmin, off, 64));
    vmax = fmaxf(vmax, __shfl_down(vmax, off, 64));
  }
  __shared__ float smin[BLOCK / 64], smax[BLOCK / 64];
  const int lane = threadIdx.x & 63, wid = threadIdx.x >> 6;
  if (lane == 0) { smin[wid] = vmin; smax[wid] = vmax; }
  __syncthreads();
  if (threadIdx.x == 0) {
    float mn = smin[0], mx = smax[0];
#pragma unroll
    for (int i = 1; i < BLOCK / 64; ++i) {
      mn = fminf(mn, smin[i]);
      mx = fmaxf(mx, smax[i]);
    }
    pmin[blockIdx.x] = mn;
    pmax[blockIdx.x] = mx;
  }
}

__global__ __launch_bounds__(512) void reduce_minmax(
    const float* __restrict__ pmin, const float* __restrict__ pmax,
    float* __restrict__ mm) {
  float vmin = INFINITY, vmax = -INFINITY;
  for (int i = threadIdx.x; i < NBLK; i += 512) {
    vmin = fminf(vmin, pmin[i]);
    vmax = fmaxf(vmax, pmax[i]);
  }
#pragma unroll
  for (int off = 32; off > 0; off >>= 1) {
    vmin = fminf(vmin, __shfl_down(vmin, off, 64));
    vmax = fmaxf(vmax, __shfl_down(vmax, off, 64));
  }
  __shared__ float smin[8], smax[8];
  const int lane = threadIdx.x & 63, wid = threadIdx.x >> 6;
  if (lane == 0) { smin[wid] = vmin; smax[wid] = vmax; }
  __syncthreads();
  if (threadIdx.x == 0) {
    float mn = smin[0], mx = smax[0];
#pragma unroll
    for (int i = 1; i < 8; ++i) {
      mn = fminf(mn, smin[i]);
      mx = fmaxf(mx, smax[i]);
    }
    mm[0] = mn;
    mm[1] = mx;
  }
}

__global__ __launch_bounds__(BLOCK) void normalize_k(
    float* __restrict__ img, const float* __restrict__ mm) {
  const int p = blockIdx.x * BLOCK + threadIdx.x;
  if (p < NPIX) {
    const float mn = mm[0], mx = mm[1];
    const float v  = img[p];
    img[p] = (mx != mn) ? (v - mn) / (mx - mn) : v;
  }
}

extern "C" void kernel_launch(void* const* d_in, const int* in_sizes, int n_in,
                              void* d_out, int out_size, void* d_ws, size_t ws_size,
                              hipStream_t stream) {
  const float* spikes = (const float*)d_in[0];
  float* out  = (float*)d_out;        // unnormalized img written here, normalized in place
  float* ws   = (float*)d_ws;
  float* mm   = ws;                   // [0]=min, [1]=max
  float* pmin = ws + 2;               // NBLK partial mins
  float* pmax = ws + 2 + NBLK;        // NBLK partial maxes

  hipLaunchKernelGGL(stp_compute, dim3(NBLK), dim3(BLOCK), 0, stream,
                     spikes, out, pmin, pmax);
  hipLaunchKernelGGL(reduce_minmax, dim3(1), dim3(512), 0, stream,
                     pmin, pmax, mm);
  hipLaunchKernelGGL(normalize_k, dim3(NBLK), dim3(BLOCK), 0, stream,
                     out, mm);
}